// Round 12
// baseline (188.550 us; speedup 1.0000x reference)
//
#include <hip/hip_runtime.h>
#include <cstddef>
#include <cstdint>

// CausalSelfAttention, bf16-MFMA pipeline, round 12.
// B=4, T=2048, C=1024, NH=16, HS=64.
//   prep:      x fp32 -> bf16  +  W fp32 [K][N] -> W^T bf16 [N][K] (fused)
//   gemm_qkv / gemm_bt: 256x128-tile, BK=64, 4-phase schedule (T3) with raw
//              s_barriers + one counted-drain vmcnt(0)/K-tile (T4-lite),
//              XOR-swizzled LDS via pre-swizzled global_load_lds source (T2),
//              setprio (T5), bm-sliced XCD map (T1). 8 waves, 96KB LDS dbuf.
//   attn_big:  round-10 version verbatim (best measured 75.8us): paired
//              128-q-tiles, KVB=128 dbuf, swapped QK^T in-lane softmax,
//              b128 PV via pi-permuted V, hoisted LDS offsets.

namespace {

typedef unsigned short u16;
typedef unsigned int u32;
typedef __attribute__((ext_vector_type(8))) short s8v;   // 8 bf16 (4 VGPR)
typedef __attribute__((ext_vector_type(4))) short s4v;   // 4 bf16 (2 VGPR)
typedef __attribute__((ext_vector_type(4))) float f4v;

constexpr int Bn = 4, Tn = 2048, Cn = 1024;
constexpr int KVB = 128;         // attn k-tile rows
constexpr int NT128 = Tn / 128;  // 16 tiles
constexpr float QSCALE = 0.125f * 1.44269504f;  // 1/sqrt(64) * log2(e)

__device__ __forceinline__ u16 bfc(float f) {  // fp32 -> bf16 (RNE, native)
  return __builtin_bit_cast(u16, (__bf16)f);
}

__device__ __forceinline__ float ex2(float x) {
#if __has_builtin(__builtin_amdgcn_exp2f)
  return __builtin_amdgcn_exp2f(x);
#else
  return exp2f(x);
#endif
}

__device__ __forceinline__ f4v mfma16(s8v a, s8v b, f4v c) {
  return __builtin_amdgcn_mfma_f32_16x16x32_bf16(a, b, c, 0, 0, 0);
}

__device__ __forceinline__ f4v mfma16k16(s4v a, s4v b, f4v c) {
#if __has_builtin(__builtin_amdgcn_mfma_f32_16x16x16bf16_1k)
  return __builtin_amdgcn_mfma_f32_16x16x16bf16_1k(a, b, c, 0, 0, 0);
#else
  f4v d = c;
  asm("v_mfma_f32_16x16x16_bf16 %0, %1, %2, %0" : "+v"(d) : "v"(a), "v"(b));
  return d;
#endif
}

typedef __attribute__((address_space(1))) const u32 gas_u32;
typedef __attribute__((address_space(3))) u32 las_u32;
__device__ __forceinline__ void gl_lds16(const void* g, void* l) {
  __builtin_amdgcn_global_load_lds((gas_u32*)g, (las_u32*)l, 16, 0, 0);
}

// ---------------- prep: cvtx (bid<4096) + wtrans (bid>=4096) ----------------
__global__ __launch_bounds__(256) void prep(
    const float* __restrict__ x, u16* __restrict__ xb,
    const float* __restrict__ w0, const float* __restrict__ w1,
    const float* __restrict__ w2, const float* __restrict__ w3,
    u16* __restrict__ o0, u16* __restrict__ o1, u16* __restrict__ o2,
    u16* __restrict__ o3) {
  __shared__ float Tsh[64][65];
  const int bid = blockIdx.x;
  const int tid = threadIdx.x;
  if (bid < 4096) {  // x -> bf16
    const size_t i = ((size_t)bid * 256 + tid) * 8;
    const float4 a = *(const float4*)(x + i);
    const float4 b = *(const float4*)(x + i + 4);
    alignas(16) u16 t[8] = {bfc(a.x), bfc(a.y), bfc(a.z), bfc(a.w),
                            bfc(b.x), bfc(b.y), bfc(b.z), bfc(b.w)};
    *(s8v*)(xb + i) = *(const s8v*)t;
    return;
  }
  const int idx = bid - 4096;  // 0..1023
  const int wz = idx >> 8, wy = (idx >> 4) & 15, wx = idx & 15;
  const float* W;
  u16* O;
  switch (wz) {
    case 0: W = w0; O = o0; break;
    case 1: W = w1; O = o1; break;
    case 2: W = w2; O = o2; break;
    default: W = w3; O = o3; break;
  }
  const int n0 = wx * 64, k0 = wy * 64;
  {
    const int rk = tid >> 2, c0 = (tid & 3) * 16;
#pragma unroll
    for (int u = 0; u < 4; ++u) {
      const float4 v = *(const float4*)&W[(size_t)(k0 + rk) * Cn + n0 + c0 + u * 4];
      Tsh[rk][c0 + u * 4 + 0] = v.x;
      Tsh[rk][c0 + u * 4 + 1] = v.y;
      Tsh[rk][c0 + u * 4 + 2] = v.z;
      Tsh[rk][c0 + u * 4 + 3] = v.w;
    }
  }
  __syncthreads();
  {
    const int rn = tid >> 2, ck0 = (tid & 3) * 16;
    alignas(16) u16 t[16];
#pragma unroll
    for (int u = 0; u < 16; ++u) t[u] = bfc(Tsh[ck0 + u][rn]);
    *(s8v*)&O[(size_t)(n0 + rn) * Cn + k0 + ck0] = *(const s8v*)&t[0];
    *(s8v*)&O[(size_t)(n0 + rn) * Cn + k0 + ck0 + 8] = *(const s8v*)&t[8];
  }
}

// ---------------- GEMM: 256x128 tile, BK=64, 4-phase schedule ----------------
// OUT_MODE 0: bf16  1: V^T head-major pi-permuted  2: fp32  3: bf16 * QSCALE
template <int OUT_MODE>
__device__ __forceinline__ void gemm_body256(
    const u16* __restrict__ A, const u16* __restrict__ Bt,
    void* __restrict__ Cout, int bm, int bn, u16* As0, u16* Bs0, u16* As1,
    u16* Bs1) {
  const int N = Cn, K = Cn;
  const int tid = threadIdx.x;           // 0..511
  const int l = tid & 63, w = tid >> 6;  // 8 waves: 4M x 2N
  const int lr = l & 15, lh = l >> 4;
  const int wm = (w >> 1) * 64, wn = (w & 1) * 64;
  const int sw = lr & 7;
  const u16* Ab = A + (size_t)bm * 256 * K;
  const u16* Bb = Bt + (size_t)bn * 128 * K;
  f4v acc[4][4] = {};

  // LDS [rows][64k] as 16B slots (row, c); slot c holds global chunk c^(row&7)
  auto stageA = [&](u16* dst, int k0, int half) {
#pragma unroll
    for (int i = 0; i < 2; ++i) {
      const int s = half * 1024 + i * 512 + tid;  // 2048 slots total
      const int r = s >> 3, c = s & 7;
      gl_lds16(Ab + (size_t)r * K + k0 + ((c ^ (r & 7)) * 8), &dst[s * 8]);
    }
  };
  auto stageB = [&](u16* dst, int k0) {
#pragma unroll
    for (int i = 0; i < 2; ++i) {
      const int s = i * 512 + tid;  // 1024 slots
      const int r = s >> 3, c = s & 7;
      gl_lds16(Bb + (size_t)r * K + k0 + ((c ^ (r & 7)) * 8), &dst[s * 8]);
    }
  };

  // prologue: tile 0
  stageA(As0, 0, 0);
  stageA(As0, 0, 1);
  stageB(Bs0, 0);
  asm volatile("s_waitcnt vmcnt(0)" ::: "memory");
  __builtin_amdgcn_s_barrier();

  // one K-tile = 4 phases; stage next tile spread over phases 0-2;
  // single vmcnt(0) drain in phase 3 (loads issued >=1 phase earlier).
  auto ktile = [&](const u16* Ac, const u16* Bc, u16* An, u16* Bnx, int k0n,
                   bool more) {
    s8v bfr[4][2];
#pragma unroll
    for (int j = 0; j < 4; ++j)
#pragma unroll
      for (int kh = 0; kh < 2; ++kh)
        bfr[j][kh] = *(const s8v*)&Bc[(wn + j * 16 + lr) * 64 +
                                      (((kh * 4 + lh) ^ sw) * 8)];
    // P0: i={0,1} k=0
    s8v a0 = *(const s8v*)&Ac[(wm + 0 + lr) * 64 + ((lh ^ sw) * 8)];
    s8v a1 = *(const s8v*)&Ac[(wm + 16 + lr) * 64 + ((lh ^ sw) * 8)];
    if (more) stageA(An, k0n, 0);
    __builtin_amdgcn_s_barrier();
    __builtin_amdgcn_s_setprio(1);
#pragma unroll
    for (int j = 0; j < 4; ++j) {
      acc[0][j] = mfma16(a0, bfr[j][0], acc[0][j]);
      acc[1][j] = mfma16(a1, bfr[j][0], acc[1][j]);
    }
    __builtin_amdgcn_s_setprio(0);
    __builtin_amdgcn_s_barrier();
    // P1: i={0,1} k=1
    a0 = *(const s8v*)&Ac[(wm + 0 + lr) * 64 + (((4 + lh) ^ sw) * 8)];
    a1 = *(const s8v*)&Ac[(wm + 16 + lr) * 64 + (((4 + lh) ^ sw) * 8)];
    if (more) stageA(An, k0n, 1);
    __builtin_amdgcn_s_barrier();
    __builtin_amdgcn_s_setprio(1);
#pragma unroll
    for (int j = 0; j < 4; ++j) {
      acc[0][j] = mfma16(a0, bfr[j][1], acc[0][j]);
      acc[1][j] = mfma16(a1, bfr[j][1], acc[1][j]);
    }
    __builtin_amdgcn_s_setprio(0);
    __builtin_amdgcn_s_barrier();
    // P2: i={2,3} k=0
    a0 = *(const s8v*)&Ac[(wm + 32 + lr) * 64 + ((lh ^ sw) * 8)];
    a1 = *(const s8v*)&Ac[(wm + 48 + lr) * 64 + ((lh ^ sw) * 8)];
    if (more) stageB(Bnx, k0n);
    __builtin_amdgcn_s_barrier();
    __builtin_amdgcn_s_setprio(1);
#pragma unroll
    for (int j = 0; j < 4; ++j) {
      acc[2][j] = mfma16(a0, bfr[j][0], acc[2][j]);
      acc[3][j] = mfma16(a1, bfr[j][0], acc[3][j]);
    }
    __builtin_amdgcn_s_setprio(0);
    __builtin_amdgcn_s_barrier();
    // P3: i={2,3} k=1; drain next-tile loads, then switch-safe barrier
    a0 = *(const s8v*)&Ac[(wm + 32 + lr) * 64 + (((4 + lh) ^ sw) * 8)];
    a1 = *(const s8v*)&Ac[(wm + 48 + lr) * 64 + (((4 + lh) ^ sw) * 8)];
    asm volatile("s_waitcnt vmcnt(0)" ::: "memory");
    __builtin_amdgcn_s_barrier();
    __builtin_amdgcn_s_setprio(1);
#pragma unroll
    for (int j = 0; j < 4; ++j) {
      acc[2][j] = mfma16(a0, bfr[j][1], acc[2][j]);
      acc[3][j] = mfma16(a1, bfr[j][1], acc[3][j]);
    }
    __builtin_amdgcn_s_setprio(0);
    __builtin_amdgcn_s_barrier();
  };

  const int NK = K / 64;  // 16
  for (int kt = 0; kt < NK; kt += 2) {
    ktile(As0, Bs0, As1, Bs1, (kt + 1) * 64, true);
    ktile(As1, Bs1, As0, Bs0, (kt + 2) * 64, kt + 2 < NK);
  }

  // Epilogue. D layout: col = lane&15, row = (lane>>4)*4 + reg  [m89]
  if (OUT_MODE == 2) {
    float* Cf = (float*)Cout;
#pragma unroll
    for (int i = 0; i < 4; ++i) {
      const int row = bm * 256 + wm + i * 16 + lh * 4;
#pragma unroll
      for (int j = 0; j < 4; ++j) {
        const int col = bn * 128 + wn + j * 16 + lr;
#pragma unroll
        for (int r = 0; r < 4; ++r)
          Cf[(size_t)(row + r) * N + col] = acc[i][j][r];
      }
    }
  } else if (OUT_MODE == 0 || OUT_MODE == 3) {
    u16* Cb = (u16*)Cout;
    const float sc = (OUT_MODE == 3) ? QSCALE : 1.0f;
#pragma unroll
    for (int i = 0; i < 4; ++i) {
      const int row = bm * 256 + wm + i * 16 + lh * 4;
#pragma unroll
      for (int j = 0; j < 4; ++j) {
        const int col = bn * 128 + wn + j * 16 + lr;
#pragma unroll
        for (int r = 0; r < 4; ++r)
          Cb[(size_t)(row + r) * N + col] = bfc(acc[i][j][r] * sc);
      }
    }
  } else {
    // V^T head-major pi-permuted: within each 128-t tile, original
    // t = 32p+16s+4lh+j stored at p*32+lh*8+s*4+j (4-groups stay contiguous)
    u16* Vt = (u16*)Cout;
#pragma unroll
    for (int i = 0; i < 4; ++i) {
      const int row0 = bm * 256 + wm + i * 16 + lh * 4;
      const int bq = row0 >> 11;
      const int t0g = row0 & 2047;
      const int tau = t0g & 127;
      const int taup = ((tau >> 5) << 5) | (((tau >> 2) & 3) << 3) |
                       (((tau >> 4) & 1) << 2);
      const int t0p = (t0g & ~127) | taup;
#pragma unroll
      for (int j = 0; j < 4; ++j) {
        const int col = bn * 128 + wn + j * 16 + lr;
        const int hh = col >> 6, dd = col & 63;
        alignas(8) u16 t4[4];
#pragma unroll
        for (int r = 0; r < 4; ++r) t4[r] = bfc(acc[i][j][r]);
        *(s4v*)&Vt[((size_t)((bq * 16 + hh) * 64 + dd)) * Tn + t0p] =
            *(const s4v*)t4;
      }
    }
  }
}

// qkv: 768 blocks = 8 XCD x (4 bm-local x 24 (which,bn)); exactly 3 CU-rounds.
__global__ __launch_bounds__(512) void gemm_qkv(
    const u16* __restrict__ A, const u16* __restrict__ btq,
    const u16* __restrict__ btk, const u16* __restrict__ btv,
    u16* __restrict__ qb, u16* __restrict__ kb, u16* __restrict__ vt) {
  __shared__ __align__(16) u16 As0[16384], Bs0[8192], As1[16384], Bs1[8192];
  const int bid = blockIdx.x;  // 0..767
  const int xcd = bid & 7, loc = bid >> 3;      // loc 0..95
  const int bm = xcd * 4 + (loc & 3);           // 0..31 (A-slice 2MB per XCD)
  const int combo = loc >> 2;                   // 0..23
  const int which = combo >> 3, bn = combo & 7;
  if (which == 0)
    gemm_body256<3>(A, btq, qb, bm, bn, As0, Bs0, As1, Bs1);  // Q pre-scaled
  else if (which == 1)
    gemm_body256<0>(A, btk, kb, bm, bn, As0, Bs0, As1, Bs1);
  else
    gemm_body256<1>(A, btv, vt, bm, bn, As0, Bs0, As1, Bs1);
}

template <int OUT_MODE>
__global__ __launch_bounds__(512) void gemm_bt(const u16* __restrict__ A,
                                               const u16* __restrict__ Bt,
                                               void* __restrict__ Cout) {
  __shared__ __align__(16) u16 As0[16384], Bs0[8192], As1[16384], Bs1[8192];
  const int bid = blockIdx.x;  // 0..255, exactly 1 CU-round
  const int xcd = bid & 7, loc = bid >> 3;  // loc 0..31
  const int bm = xcd * 4 + (loc & 3);
  const int bn = loc >> 2;  // 0..7
  gemm_body256<OUT_MODE>(A, Bt, Cout, bm, bn, As0, Bs0, As1, Bs1);
}

// ---------------- Flash attention (round-10 version, verbatim) ----------------
__device__ __forceinline__ void stage_kv(const u16* __restrict__ kgb,
                                         const u16* __restrict__ vtb,
                                         u16* __restrict__ Kb,
                                         u16* __restrict__ Vb, int k0,
                                         int tid) {
#pragma unroll
  for (int is = 0; is < 2; ++is) {
    const int slot = is * 512 + tid;
    const int row = slot >> 3, ch = slot & 7;
    gl_lds16(kgb + (size_t)(k0 + row) * Cn + ((ch ^ (row & 7)) * 8),
             &Kb[slot * 8]);
  }
#pragma unroll
  for (int is = 0; is < 2; ++is) {
    const int slot = is * 512 + tid;
    const int d = slot >> 4, ch = slot & 15;
    gl_lds16(vtb + (size_t)d * Tn + k0 + ((ch ^ (d & 7)) * 8), &Vb[slot * 8]);
  }
}

__device__ __forceinline__ void attn_step(const s8v (&aq)[2],
                                          const u16* __restrict__ Ks,
                                          const u16* __restrict__ Vs, int kb0,
                                          int kb1, const int (&vch)[4], int ln,
                                          int lh, bool diag, int k0, int qg,
                                          float& m_i, float& l_i, f4v* o) {
  f4v s[8] = {};
  __builtin_amdgcn_s_setprio(1);
#pragma unroll
  for (int n = 0; n < 8; ++n) {
    const s8v bk0 = *(const s8v*)&Ks[kb0 + n * 1024];
    const s8v bk1 = *(const s8v*)&Ks[kb1 + n * 1024];
    s[n] = mfma16(bk0, aq[0], s[n]);  // SWAPPED: S^T[k][q]
    s[n] = mfma16(bk1, aq[1], s[n]);
  }
  __builtin_amdgcn_s_setprio(0);
  float rm = -1e30f;
  if (diag) {
#pragma unroll
    for (int n = 0; n < 8; ++n)
#pragma unroll
      for (int r = 0; r < 4; ++r) {
        float x = s[n][r];
        if (k0 + n * 16 + lh * 4 + r > qg) x = -1e30f;
        s[n][r] = x;
        rm = fmaxf(rm, x);
      }
  } else {
#pragma unroll
    for (int n = 0; n < 8; ++n)
      rm = fmaxf(rm, fmaxf(fmaxf(s[n][0], s[n][1]), fmaxf(s[n][2], s[n][3])));
  }
  if (!__all(rm <= m_i + 11.5f)) {  // T13 defer-max
    float rr = fmaxf(rm, __shfl_xor(rm, 16));
    rr = fmaxf(rr, __shfl_xor(rr, 32));
    const float mnew = fmaxf(m_i, rr);
    const float al = ex2(m_i - mnew);
    m_i = mnew;
    l_i *= al;
#pragma unroll
    for (int r = 0; r < 4; ++r) {
      const float ar = __shfl(al, (ln & 48) | (lh * 4 + r));
#pragma unroll
      for (int n2 = 0; n2 < 4; ++n2) o[n2][r] *= ar;
    }
  }
  s4v pa[8];
  float rs = 0.f;
#pragma unroll
  for (int n = 0; n < 8; ++n) {
    const float p0 = ex2(s[n][0] - m_i);
    const float p1 = ex2(s[n][1] - m_i);
    const float p2 = ex2(s[n][2] - m_i);
    const float p3 = ex2(s[n][3] - m_i);
    rs += (p0 + p1) + (p2 + p3);
    pa[n] = (s4v){(short)bfc(p0), (short)bfc(p1), (short)bfc(p2),
                  (short)bfc(p3)};
  }
  l_i += rs;
  __builtin_amdgcn_s_setprio(1);
#pragma unroll
  for (int n2 = 0; n2 < 4; ++n2) {
#pragma unroll
    for (int p = 0; p < 4; ++p) {
      const s8v vv = *(const s8v*)&Vs[vch[p] + n2 * 2048];
      const s4v lo = {vv[0], vv[1], vv[2], vv[3]};
      const s4v hi = {vv[4], vv[5], vv[6], vv[7]};
      o[n2] = mfma16k16(pa[2 * p], lo, o[n2]);
      o[n2] = mfma16k16(pa[2 * p + 1], hi, o[n2]);
    }
  }
  __builtin_amdgcn_s_setprio(0);
}

__global__ __launch_bounds__(512) void attn_big(const u16* __restrict__ qg,
                                                const u16* __restrict__ kg,
                                                const u16* __restrict__ vtg,
                                                u16* __restrict__ yg) {
  __shared__ __align__(16) u16 Ks0[KVB * 64], Ks1[KVB * 64];  // 16 KB each
  __shared__ __align__(16) u16 Vs0[64 * KVB], Vs1[64 * KVB];  // 16 KB each
  const int tid = threadIdx.x;
  const int ln = tid & 63, w = tid >> 6;  // wave 0..7
  const int lr = ln & 15, lh = ln >> 4;
  const int bid = blockIdx.x;                  // 0..511
  const int wg = (bid & 7) * 64 + (bid >> 3);  // XCD chunking (512 % 8 == 0)
  const int bh = wg >> 3, xp = wg & 7;
  const int b = bh >> 4, h = bh & 15;
  const int tL = xp, tH = NT128 - 1 - xp;
  const int q0L = tL * 128, q0H = tH * 128;
  const u16* kgb = kg + (size_t)(b * Tn) * Cn + h * 64;
  const u16* vtb = vtg + (size_t)(bh * 64) * Tn;
  const int kb0 = lr * 64 + ((lh) ^ (lr & 7)) * 8;
  const int kb1 = lr * 64 + ((4 + lh) ^ (lr & 7)) * 8;
  int vch[4];
#pragma unroll
  for (int p = 0; p < 4; ++p)
    vch[p] = lr * 128 + ((p * 4 + lh) ^ (lr & 7)) * 8;
  s8v aqL[2], aqH[2];
  {
    const int row = w * 16 + lr;
#pragma unroll
    for (int kd = 0; kd < 2; ++kd) {
      aqL[kd] = *(const s8v*)&qg[(size_t)(b * Tn + q0L + row) * Cn + h * 64 +
                                 kd * 32 + lh * 8];
      aqH[kd] = *(const s8v*)&qg[(size_t)(b * Tn + q0H + row) * Cn + h * 64 +
                                 kd * 32 + lh * 8];
    }
  }
  const int qgH = q0H + w * 16 + lr;
  const int qgL = q0L + w * 16 + lr;
  float mL = -1e30f, lL = 0.f, mH = -1e30f, lH = 0.f;
  f4v oL[4] = {}, oH[4] = {};
  stage_kv(kgb, vtb, Ks0, Vs0, 0, tid);
  __syncthreads();  // buf0 ready (barrier drains vmcnt)
  for (int kt = 0; kt <= tH; ++kt) {
    const bool cur = kt & 1;
    const u16* Kb = cur ? Ks1 : Ks0;
    const u16* Vb = cur ? Vs1 : Vs0;
    if (kt < tH)
      stage_kv(kgb, vtb, cur ? Ks0 : Ks1, cur ? Vs0 : Vs1, (kt + 1) * KVB,
               tid);
    attn_step(aqH, Kb, Vb, kb0, kb1, vch, ln, lh, kt == tH, kt * KVB, qgH, mH,
              lH, oH);
    if (kt <= tL)
      attn_step(aqL, Kb, Vb, kb0, kb1, vch, ln, lh, kt == tL, kt * KVB, qgL,
                mL, lL, oL);
    __syncthreads();
  }
  {
    float ls = lH;
    ls += __shfl_xor(ls, 16);
    ls += __shfl_xor(ls, 32);
    const float linv = 1.0f / ls;
#pragma unroll
    for (int r = 0; r < 4; ++r) {
      const float iv = __shfl(linv, (ln & 48) | (lh * 4 + r));
      const int row = q0H + w * 16 + lh * 4 + r;
#pragma unroll
      for (int n2 = 0; n2 < 4; ++n2)
        yg[(size_t)(b * Tn + row) * Cn + h * 64 + n2 * 16 + lr] =
            bfc(oH[n2][r] * iv);
    }
  }
  {
    float ls = lL;
    ls += __shfl_xor(ls, 16);
    ls += __shfl_xor(ls, 32);
    const float linv = 1.0f / ls;
#pragma unroll
    for (int r = 0; r < 4; ++r) {
      const float iv = __shfl(linv, (ln & 48) | (lh * 4 + r));
      const int row = q0L + w * 16 + lh * 4 + r;
#pragma unroll
      for (int n2 = 0; n2 < 4; ++n2)
        yg[(size_t)(b * Tn + row) * Cn + h * 64 + n2 * 16 + lr] =
            bfc(oL[n2][r] * iv);
    }
  }
}

}  // namespace

extern "C" void kernel_launch(void* const* d_in, const int* in_sizes, int n_in,
                              void* d_out, int out_size, void* d_ws,
                              size_t ws_size, hipStream_t stream) {
  (void)in_sizes; (void)n_in; (void)out_size; (void)ws_size;
  const float* x = (const float*)d_in[0];
  const float* Wk = (const float*)d_in[1];
  const float* Wq = (const float*)d_in[2];
  const float* Wv = (const float*)d_in[3];
  const float* Wp = (const float*)d_in[4];
  float* out = (float*)d_out;
  char* ws = (char*)d_ws;

  u16* xb = (u16*)(ws);              // 16.8 MB
  u16* wqt = (u16*)(ws + 16777216);  // 2 MB each
  u16* wkt = (u16*)(ws + 18874368);
  u16* wvt = (u16*)(ws + 20971520);
  u16* wpt = (u16*)(ws + 23068672);
  u16* qb = (u16*)(ws + 25165824);  // 16.8 MB each
  u16* kb = (u16*)(ws + 41943040);
  u16* vt = (u16*)(ws + 58720256);  // head-major V^T [b][h][d][t], pi-permuted
  u16* yb = (u16*)(ws + 75497472);

  prep<<<dim3(5120), dim3(256), 0, stream>>>(x, xb, Wq, Wk, Wv, Wp, wqt, wkt,
                                             wvt, wpt);
  gemm_qkv<<<dim3(768), dim3(512), 0, stream>>>(xb, wqt, wkt, wvt, qb, kb,
                                                vt);
  attn_big<<<dim3(512), dim3(512), 0, stream>>>(qb, kb, vt, yb);
  gemm_bt<2><<<dim3(256), dim3(512), 0, stream>>>(yb, wpt, out);
}

// Round 13
// 168.517 us; speedup vs baseline: 1.1189x; 1.1189x over previous
//
#include <hip/hip_runtime.h>
#include <cstddef>
#include <cstdint>

// CausalSelfAttention, bf16-MFMA pipeline, round 13 = round 10 restored
// (best measured: 169.0 us). Rounds 11/12 experiments regressed and are
// reverted; their post-mortems: KVB=64 halved MFMA-per-barrier (m233-style
// stage+barrier domination), 4-phase GEMM used drain-0 vmcnt (m218 V1 =
// no gain) at 1 block/CU (barrier gaps unfillable).
// B=4, T=2048, C=1024, NH=16, HS=64.
//   prep:      x fp32 -> bf16  +  W fp32 [K][N] -> W^T bf16 [N][K] (fused)
//   gemm_qkv:  fused q/k/v projection; BK=64, XOR-swizzled LDS, bm-sliced XCD
//   gemm_bt<2>: output projection
//   attn_big:  paired 128-q-tiles (xp,15-xp), KVB=128 dbuf, swapped QK^T
//              in-lane softmax, b128 PV via pi-permuted V, hoisted offsets.

namespace {

typedef unsigned short u16;
typedef unsigned int u32;
typedef __attribute__((ext_vector_type(8))) short s8v;   // 8 bf16 (4 VGPR)
typedef __attribute__((ext_vector_type(4))) short s4v;   // 4 bf16 (2 VGPR)
typedef __attribute__((ext_vector_type(4))) float f4v;

constexpr int Bn = 4, Tn = 2048, Cn = 1024;
constexpr int KVB = 128;         // attn k-tile rows
constexpr int NT128 = Tn / 128;  // 16 tiles
constexpr float QSCALE = 0.125f * 1.44269504f;  // 1/sqrt(64) * log2(e)

__device__ __forceinline__ u16 bfc(float f) {  // fp32 -> bf16 (RNE, native)
  return __builtin_bit_cast(u16, (__bf16)f);
}

__device__ __forceinline__ float ex2(float x) {
#if __has_builtin(__builtin_amdgcn_exp2f)
  return __builtin_amdgcn_exp2f(x);
#else
  return exp2f(x);
#endif
}

__device__ __forceinline__ f4v mfma16(s8v a, s8v b, f4v c) {
  return __builtin_amdgcn_mfma_f32_16x16x32_bf16(a, b, c, 0, 0, 0);
}

__device__ __forceinline__ f4v mfma16k16(s4v a, s4v b, f4v c) {
#if __has_builtin(__builtin_amdgcn_mfma_f32_16x16x16bf16_1k)
  return __builtin_amdgcn_mfma_f32_16x16x16bf16_1k(a, b, c, 0, 0, 0);
#else
  f4v d = c;
  asm("v_mfma_f32_16x16x16_bf16 %0, %1, %2, %0" : "+v"(d) : "v"(a), "v"(b));
  return d;
#endif
}

typedef __attribute__((address_space(1))) const u32 gas_u32;
typedef __attribute__((address_space(3))) u32 las_u32;
__device__ __forceinline__ void gl_lds16(const void* g, void* l) {
  __builtin_amdgcn_global_load_lds((gas_u32*)g, (las_u32*)l, 16, 0, 0);
}

// ---------------- prep: cvtx (bid<4096) + wtrans (bid>=4096) ----------------
__global__ __launch_bounds__(256) void prep(
    const float* __restrict__ x, u16* __restrict__ xb,
    const float* __restrict__ w0, const float* __restrict__ w1,
    const float* __restrict__ w2, const float* __restrict__ w3,
    u16* __restrict__ o0, u16* __restrict__ o1, u16* __restrict__ o2,
    u16* __restrict__ o3) {
  __shared__ float Tsh[64][65];
  const int bid = blockIdx.x;
  const int tid = threadIdx.x;
  if (bid < 4096) {  // x -> bf16
    const size_t i = ((size_t)bid * 256 + tid) * 8;
    const float4 a = *(const float4*)(x + i);
    const float4 b = *(const float4*)(x + i + 4);
    alignas(16) u16 t[8] = {bfc(a.x), bfc(a.y), bfc(a.z), bfc(a.w),
                            bfc(b.x), bfc(b.y), bfc(b.z), bfc(b.w)};
    *(s8v*)(xb + i) = *(const s8v*)t;
    return;
  }
  const int idx = bid - 4096;  // 0..1023
  const int wz = idx >> 8, wy = (idx >> 4) & 15, wx = idx & 15;
  const float* W;
  u16* O;
  switch (wz) {
    case 0: W = w0; O = o0; break;
    case 1: W = w1; O = o1; break;
    case 2: W = w2; O = o2; break;
    default: W = w3; O = o3; break;
  }
  const int n0 = wx * 64, k0 = wy * 64;
  {
    const int rk = tid >> 2, c0 = (tid & 3) * 16;
#pragma unroll
    for (int u = 0; u < 4; ++u) {
      const float4 v = *(const float4*)&W[(size_t)(k0 + rk) * Cn + n0 + c0 + u * 4];
      Tsh[rk][c0 + u * 4 + 0] = v.x;
      Tsh[rk][c0 + u * 4 + 1] = v.y;
      Tsh[rk][c0 + u * 4 + 2] = v.z;
      Tsh[rk][c0 + u * 4 + 3] = v.w;
    }
  }
  __syncthreads();
  {
    const int rn = tid >> 2, ck0 = (tid & 3) * 16;
    alignas(16) u16 t[16];
#pragma unroll
    for (int u = 0; u < 16; ++u) t[u] = bfc(Tsh[ck0 + u][rn]);
    *(s8v*)&O[(size_t)(n0 + rn) * Cn + k0 + ck0] = *(const s8v*)&t[0];
    *(s8v*)&O[(size_t)(n0 + rn) * Cn + k0 + ck0 + 8] = *(const s8v*)&t[8];
  }
}

// ---------------- GEMM body: BK=64, XOR-swizzled LDS ----------------
// OUT_MODE 0: bf16  1: V^T head-major pi-permuted  2: fp32  3: bf16 * QSCALE
template <int OUT_MODE>
__device__ __forceinline__ void gemm_body(const u16* __restrict__ A,
                                          const u16* __restrict__ Bt,
                                          void* __restrict__ Cout, int bm,
                                          int bn, u16* As, u16* Bs) {
  const int N = Cn, K = Cn;
  const int tid = threadIdx.x;
  const int l = tid & 63, w = tid >> 6;
  const int lr = l & 15, lh = l >> 4;
  const int wm = (w >> 1) * 64, wn = (w & 1) * 64;
  const u16* Ab = A + (size_t)(bm * 128) * K;
  const u16* Bb = Bt + (size_t)(bn * 128) * K;
  const int sw = lr & 7;
  f4v acc[4][4] = {};
  for (int k0 = 0; k0 < K; k0 += 64) {
    __syncthreads();  // readers done with LDS
#pragma unroll
    for (int i = 0; i < 4; ++i) {
      const int s = tid + 256 * i;
      const int r = s >> 3, c = s & 7;
      gl_lds16(Ab + (size_t)r * K + k0 + ((c ^ (r & 7)) * 8), &As[s * 8]);
    }
#pragma unroll
    for (int i = 0; i < 4; ++i) {
      const int s = tid + 256 * i;
      const int r = s >> 3, c = s & 7;
      gl_lds16(Bb + (size_t)r * K + k0 + ((c ^ (r & 7)) * 8), &Bs[s * 8]);
    }
    __syncthreads();  // stage complete (barrier drains vmcnt)
#pragma unroll
    for (int half = 0; half < 2; ++half) {
      s8v af[4], bfr[4];
#pragma unroll
      for (int i = 0; i < 4; ++i)
        af[i] = *(const s8v*)&As[(wm + i * 16 + lr) * 64 +
                                 (((half * 4 + lh) ^ sw) * 8)];
#pragma unroll
      for (int j = 0; j < 4; ++j)
        bfr[j] = *(const s8v*)&Bs[(wn + j * 16 + lr) * 64 +
                                  (((half * 4 + lh) ^ sw) * 8)];
      __builtin_amdgcn_s_setprio(1);
#pragma unroll
      for (int i = 0; i < 4; ++i)
#pragma unroll
        for (int j = 0; j < 4; ++j)
          acc[i][j] = mfma16(af[i], bfr[j], acc[i][j]);
      __builtin_amdgcn_s_setprio(0);
    }
  }
  // D layout: col = lane&15, row = (lane>>4)*4 + reg  [m89]
  if (OUT_MODE == 2) {
    float* Cf = (float*)Cout;
#pragma unroll
    for (int i = 0; i < 4; ++i) {
      const int row = bm * 128 + wm + i * 16 + lh * 4;
#pragma unroll
      for (int j = 0; j < 4; ++j) {
        const int col = bn * 128 + wn + j * 16 + lr;
#pragma unroll
        for (int r = 0; r < 4; ++r)
          Cf[(size_t)(row + r) * N + col] = acc[i][j][r];
      }
    }
  } else if (OUT_MODE == 0 || OUT_MODE == 3) {
    u16* Cb = (u16*)Cout;
    const float sc = (OUT_MODE == 3) ? QSCALE : 1.0f;
#pragma unroll
    for (int i = 0; i < 4; ++i) {
      const int row = bm * 128 + wm + i * 16 + lh * 4;
#pragma unroll
      for (int j = 0; j < 4; ++j) {
        const int col = bn * 128 + wn + j * 16 + lr;
#pragma unroll
        for (int r = 0; r < 4; ++r)
          Cb[(size_t)(row + r) * N + col] = bfc(acc[i][j][r] * sc);
      }
    }
  } else {
    // V^T head-major pi-permuted: within each 128-t tile, original
    // t = 32p+16s+4lh+j stored at p*32+lh*8+s*4+j (4-groups stay contiguous)
    u16* Vt = (u16*)Cout;
#pragma unroll
    for (int i = 0; i < 4; ++i) {
      const int row0 = bm * 128 + wm + i * 16 + lh * 4;
      const int bq = row0 >> 11;
      const int t0g = row0 & 2047;
      const int tau = t0g & 127;
      const int taup = ((tau >> 5) << 5) | (((tau >> 2) & 3) << 3) |
                       (((tau >> 4) & 1) << 2);
      const int t0p = (t0g & ~127) | taup;
#pragma unroll
      for (int j = 0; j < 4; ++j) {
        const int col = bn * 128 + wn + j * 16 + lr;
        const int hh = col >> 6, dd = col & 63;
        alignas(8) u16 t4[4];
#pragma unroll
        for (int r = 0; r < 4; ++r) t4[r] = bfc(acc[i][j][r]);
        *(s4v*)&Vt[((size_t)((bq * 16 + hh) * 64 + dd)) * Tn + t0p] =
            *(const s4v*)t4;
      }
    }
  }
}

// Fused q/k/v projection: 1536 blocks. bm-sliced XCD map: each XCD owns
// bm in [xcd*8, xcd*8+8) (A-slice 2MB -> stays in 4MB L2); (which,bn)
// combos iterate with bm-local fastest (B panel hot for 8 blocks).
__global__ __launch_bounds__(256) void gemm_qkv(
    const u16* __restrict__ A, const u16* __restrict__ btq,
    const u16* __restrict__ btk, const u16* __restrict__ btv,
    u16* __restrict__ qb, u16* __restrict__ kb, u16* __restrict__ vt) {
  __shared__ __align__(16) u16 As[8192], Bs[8192];  // 32 KB
  const int bid = blockIdx.x;  // 0..1535
  const int xcd = bid & 7, j = bid >> 3;
  const int bm = xcd * 8 + (j & 7);
  const int combo = j >> 3;  // 0..23
  const int which = combo >> 3, bn = combo & 7;
  if (which == 0)
    gemm_body<3>(A, btq, qb, bm, bn, As, Bs);  // Q pre-scaled
  else if (which == 1)
    gemm_body<0>(A, btk, kb, bm, bn, As, Bs);
  else
    gemm_body<1>(A, btv, vt, bm, bn, As, Bs);
}

template <int OUT_MODE>
__global__ __launch_bounds__(256) void gemm_bt(const u16* __restrict__ A,
                                               const u16* __restrict__ Bt,
                                               void* __restrict__ Cout) {
  __shared__ __align__(16) u16 As[8192], Bs[8192];  // 32 KB
  const int bid = blockIdx.x;  // 0..511
  const int xcd = bid & 7, j = bid >> 3;
  const int bm = xcd * 8 + (j & 7);
  const int bn = j >> 3;  // 0..7
  gemm_body<OUT_MODE>(A, Bt, Cout, bm, bn, As, Bs);
}

// ---------------- Flash attention (round-10 version) ----------------
__device__ __forceinline__ void stage_kv(const u16* __restrict__ kgb,
                                         const u16* __restrict__ vtb,
                                         u16* __restrict__ Kb,
                                         u16* __restrict__ Vb, int k0,
                                         int tid) {
#pragma unroll
  for (int is = 0; is < 2; ++is) {
    const int slot = is * 512 + tid;
    const int row = slot >> 3, ch = slot & 7;
    gl_lds16(kgb + (size_t)(k0 + row) * Cn + ((ch ^ (row & 7)) * 8),
             &Kb[slot * 8]);
  }
#pragma unroll
  for (int is = 0; is < 2; ++is) {
    const int slot = is * 512 + tid;
    const int d = slot >> 4, ch = slot & 15;
    gl_lds16(vtb + (size_t)d * Tn + k0 + ((ch ^ (d & 7)) * 8), &Vb[slot * 8]);
  }
}

__device__ __forceinline__ void attn_step(const s8v (&aq)[2],
                                          const u16* __restrict__ Ks,
                                          const u16* __restrict__ Vs, int kb0,
                                          int kb1, const int (&vch)[4], int ln,
                                          int lh, bool diag, int k0, int qg,
                                          float& m_i, float& l_i, f4v* o) {
  f4v s[8] = {};
  __builtin_amdgcn_s_setprio(1);
#pragma unroll
  for (int n = 0; n < 8; ++n) {
    const s8v bk0 = *(const s8v*)&Ks[kb0 + n * 1024];
    const s8v bk1 = *(const s8v*)&Ks[kb1 + n * 1024];
    s[n] = mfma16(bk0, aq[0], s[n]);  // SWAPPED: S^T[k][q]
    s[n] = mfma16(bk1, aq[1], s[n]);
  }
  __builtin_amdgcn_s_setprio(0);
  float rm = -1e30f;
  if (diag) {
#pragma unroll
    for (int n = 0; n < 8; ++n)
#pragma unroll
      for (int r = 0; r < 4; ++r) {
        float x = s[n][r];
        if (k0 + n * 16 + lh * 4 + r > qg) x = -1e30f;
        s[n][r] = x;
        rm = fmaxf(rm, x);
      }
  } else {
#pragma unroll
    for (int n = 0; n < 8; ++n)
      rm = fmaxf(rm, fmaxf(fmaxf(s[n][0], s[n][1]), fmaxf(s[n][2], s[n][3])));
  }
  if (!__all(rm <= m_i + 11.5f)) {  // T13 defer-max
    float rr = fmaxf(rm, __shfl_xor(rm, 16));
    rr = fmaxf(rr, __shfl_xor(rr, 32));
    const float mnew = fmaxf(m_i, rr);
    const float al = ex2(m_i - mnew);
    m_i = mnew;
    l_i *= al;
#pragma unroll
    for (int r = 0; r < 4; ++r) {
      const float ar = __shfl(al, (ln & 48) | (lh * 4 + r));
#pragma unroll
      for (int n2 = 0; n2 < 4; ++n2) o[n2][r] *= ar;
    }
  }
  s4v pa[8];
  float rs = 0.f;
#pragma unroll
  for (int n = 0; n < 8; ++n) {
    const float p0 = ex2(s[n][0] - m_i);
    const float p1 = ex2(s[n][1] - m_i);
    const float p2 = ex2(s[n][2] - m_i);
    const float p3 = ex2(s[n][3] - m_i);
    rs += (p0 + p1) + (p2 + p3);
    pa[n] = (s4v){(short)bfc(p0), (short)bfc(p1), (short)bfc(p2),
                  (short)bfc(p3)};
  }
  l_i += rs;
  __builtin_amdgcn_s_setprio(1);
#pragma unroll
  for (int n2 = 0; n2 < 4; ++n2) {
#pragma unroll
    for (int p = 0; p < 4; ++p) {
      const s8v vv = *(const s8v*)&Vs[vch[p] + n2 * 2048];
      const s4v lo = {vv[0], vv[1], vv[2], vv[3]};
      const s4v hi = {vv[4], vv[5], vv[6], vv[7]};
      o[n2] = mfma16k16(pa[2 * p], lo, o[n2]);
      o[n2] = mfma16k16(pa[2 * p + 1], hi, o[n2]);
    }
  }
  __builtin_amdgcn_s_setprio(0);
}

__global__ __launch_bounds__(512) void attn_big(const u16* __restrict__ qg,
                                                const u16* __restrict__ kg,
                                                const u16* __restrict__ vtg,
                                                u16* __restrict__ yg) {
  __shared__ __align__(16) u16 Ks0[KVB * 64], Ks1[KVB * 64];  // 16 KB each
  __shared__ __align__(16) u16 Vs0[64 * KVB], Vs1[64 * KVB];  // 16 KB each
  const int tid = threadIdx.x;
  const int ln = tid & 63, w = tid >> 6;  // wave 0..7
  const int lr = ln & 15, lh = ln >> 4;
  const int bid = blockIdx.x;                  // 0..511
  const int wg = (bid & 7) * 64 + (bid >> 3);  // XCD chunking (512 % 8 == 0)
  const int bh = wg >> 3, xp = wg & 7;
  const int b = bh >> 4, h = bh & 15;
  const int tL = xp, tH = NT128 - 1 - xp;
  const int q0L = tL * 128, q0H = tH * 128;
  const u16* kgb = kg + (size_t)(b * Tn) * Cn + h * 64;
  const u16* vtb = vtg + (size_t)(bh * 64) * Tn;
  const int kb0 = lr * 64 + ((lh) ^ (lr & 7)) * 8;
  const int kb1 = lr * 64 + ((4 + lh) ^ (lr & 7)) * 8;
  int vch[4];
#pragma unroll
  for (int p = 0; p < 4; ++p)
    vch[p] = lr * 128 + ((p * 4 + lh) ^ (lr & 7)) * 8;
  s8v aqL[2], aqH[2];
  {
    const int row = w * 16 + lr;
#pragma unroll
    for (int kd = 0; kd < 2; ++kd) {
      aqL[kd] = *(const s8v*)&qg[(size_t)(b * Tn + q0L + row) * Cn + h * 64 +
                                 kd * 32 + lh * 8];
      aqH[kd] = *(const s8v*)&qg[(size_t)(b * Tn + q0H + row) * Cn + h * 64 +
                                 kd * 32 + lh * 8];
    }
  }
  const int qgH = q0H + w * 16 + lr;
  const int qgL = q0L + w * 16 + lr;
  float mL = -1e30f, lL = 0.f, mH = -1e30f, lH = 0.f;
  f4v oL[4] = {}, oH[4] = {};
  stage_kv(kgb, vtb, Ks0, Vs0, 0, tid);
  __syncthreads();  // buf0 ready (barrier drains vmcnt)
  for (int kt = 0; kt <= tH; ++kt) {
    const bool cur = kt & 1;
    const u16* Kb = cur ? Ks1 : Ks0;
    const u16* Vb = cur ? Vs1 : Vs0;
    if (kt < tH)
      stage_kv(kgb, vtb, cur ? Ks0 : Ks1, cur ? Vs0 : Vs1, (kt + 1) * KVB,
               tid);
    attn_step(aqH, Kb, Vb, kb0, kb1, vch, ln, lh, kt == tH, kt * KVB, qgH, mH,
              lH, oH);
    if (kt <= tL)
      attn_step(aqL, Kb, Vb, kb0, kb1, vch, ln, lh, kt == tL, kt * KVB, qgL,
                mL, lL, oL);
    __syncthreads();
  }
  {
    float ls = lH;
    ls += __shfl_xor(ls, 16);
    ls += __shfl_xor(ls, 32);
    const float linv = 1.0f / ls;
#pragma unroll
    for (int r = 0; r < 4; ++r) {
      const float iv = __shfl(linv, (ln & 48) | (lh * 4 + r));
      const int row = q0H + w * 16 + lh * 4 + r;
#pragma unroll
      for (int n2 = 0; n2 < 4; ++n2)
        yg[(size_t)(b * Tn + row) * Cn + h * 64 + n2 * 16 + lr] =
            bfc(oH[n2][r] * iv);
    }
  }
  {
    float ls = lL;
    ls += __shfl_xor(ls, 16);
    ls += __shfl_xor(ls, 32);
    const float linv = 1.0f / ls;
#pragma unroll
    for (int r = 0; r < 4; ++r) {
      const float iv = __shfl(linv, (ln & 48) | (lh * 4 + r));
      const int row = q0L + w * 16 + lh * 4 + r;
#pragma unroll
      for (int n2 = 0; n2 < 4; ++n2)
        yg[(size_t)(b * Tn + row) * Cn + h * 64 + n2 * 16 + lr] =
            bfc(oL[n2][r] * iv);
    }
  }
}

}  // namespace

extern "C" void kernel_launch(void* const* d_in, const int* in_sizes, int n_in,
                              void* d_out, int out_size, void* d_ws,
                              size_t ws_size, hipStream_t stream) {
  (void)in_sizes; (void)n_in; (void)out_size; (void)ws_size;
  const float* x = (const float*)d_in[0];
  const float* Wk = (const float*)d_in[1];
  const float* Wq = (const float*)d_in[2];
  const float* Wv = (const float*)d_in[3];
  const float* Wp = (const float*)d_in[4];
  float* out = (float*)d_out;
  char* ws = (char*)d_ws;

  u16* xb = (u16*)(ws);              // 16.8 MB
  u16* wqt = (u16*)(ws + 16777216);  // 2 MB each
  u16* wkt = (u16*)(ws + 18874368);
  u16* wvt = (u16*)(ws + 20971520);
  u16* wpt = (u16*)(ws + 23068672);
  u16* qb = (u16*)(ws + 25165824);  // 16.8 MB each
  u16* kb = (u16*)(ws + 41943040);
  u16* vt = (u16*)(ws + 58720256);  // head-major V^T [b][h][d][t], pi-permuted
  u16* yb = (u16*)(ws + 75497472);

  prep<<<dim3(5120), dim3(256), 0, stream>>>(x, xb, Wq, Wk, Wv, Wp, wqt, wkt,
                                             wvt, wpt);
  gemm_qkv<<<dim3(1536), dim3(256), 0, stream>>>(xb, wqt, wkt, wvt, qb, kb,
                                                 vt);
  attn_big<<<dim3(512), dim3(512), 0, stream>>>(qb, kb, vt, yb);
  gemm_bt<2><<<dim3(512), dim3(256), 0, stream>>>(yb, wpt, out);
}

// Round 14
// 168.462 us; speedup vs baseline: 1.1192x; 1.0003x over previous
//
#include <hip/hip_runtime.h>
#include <cstddef>
#include <cstdint>

// CausalSelfAttention, bf16-MFMA pipeline, round 14.
// B=4, T=2048, C=1024, NH=16, HS=64.
//   prep:      x fp32 -> bf16  +  W fp32 [K][N] -> W^T bf16 [N][K] (fused)
//   gemm 8p:   256x128 tile, BK=64, 4-phase/K-tile schedule with 3-deep
//              K-tile circular LDS (144KB), counted vmcnt(6) (never 0 in
//              main loop), raw s_barriers, setprio, XOR-swizzled LDS via
//              pre-swizzled global_load_lds source, bm-sliced XCD map.
//              Race-freedom: stage target buf[(j+2)%3] = tile j-1's buffer
//              (reads done before tile j began); tile j+1's loads are
//              always older than tile j's 6 in-flight -> vmcnt(6) at
//              phase 3 + barrier guarantees readiness.
//   attn_big:  round-10 version verbatim (best measured 75.8us).

namespace {

typedef unsigned short u16;
typedef unsigned int u32;
typedef __attribute__((ext_vector_type(8))) short s8v;   // 8 bf16 (4 VGPR)
typedef __attribute__((ext_vector_type(4))) short s4v;   // 4 bf16 (2 VGPR)
typedef __attribute__((ext_vector_type(4))) float f4v;

constexpr int Bn = 4, Tn = 2048, Cn = 1024;
constexpr int KVB = 128;         // attn k-tile rows
constexpr int NT128 = Tn / 128;  // 16 tiles
constexpr float QSCALE = 0.125f * 1.44269504f;  // 1/sqrt(64) * log2(e)

__device__ __forceinline__ u16 bfc(float f) {  // fp32 -> bf16 (RNE, native)
  return __builtin_bit_cast(u16, (__bf16)f);
}

__device__ __forceinline__ float ex2(float x) {
#if __has_builtin(__builtin_amdgcn_exp2f)
  return __builtin_amdgcn_exp2f(x);
#else
  return exp2f(x);
#endif
}

__device__ __forceinline__ f4v mfma16(s8v a, s8v b, f4v c) {
  return __builtin_amdgcn_mfma_f32_16x16x32_bf16(a, b, c, 0, 0, 0);
}

__device__ __forceinline__ f4v mfma16k16(s4v a, s4v b, f4v c) {
#if __has_builtin(__builtin_amdgcn_mfma_f32_16x16x16bf16_1k)
  return __builtin_amdgcn_mfma_f32_16x16x16bf16_1k(a, b, c, 0, 0, 0);
#else
  f4v d = c;
  asm("v_mfma_f32_16x16x16_bf16 %0, %1, %2, %0" : "+v"(d) : "v"(a), "v"(b));
  return d;
#endif
}

typedef __attribute__((address_space(1))) const u32 gas_u32;
typedef __attribute__((address_space(3))) u32 las_u32;
__device__ __forceinline__ void gl_lds16(const void* g, void* l) {
  __builtin_amdgcn_global_load_lds((gas_u32*)g, (las_u32*)l, 16, 0, 0);
}

// ---------------- prep: cvtx (bid<4096) + wtrans (bid>=4096) ----------------
__global__ __launch_bounds__(256) void prep(
    const float* __restrict__ x, u16* __restrict__ xb,
    const float* __restrict__ w0, const float* __restrict__ w1,
    const float* __restrict__ w2, const float* __restrict__ w3,
    u16* __restrict__ o0, u16* __restrict__ o1, u16* __restrict__ o2,
    u16* __restrict__ o3) {
  __shared__ float Tsh[64][65];
  const int bid = blockIdx.x;
  const int tid = threadIdx.x;
  if (bid < 4096) {  // x -> bf16
    const size_t i = ((size_t)bid * 256 + tid) * 8;
    const float4 a = *(const float4*)(x + i);
    const float4 b = *(const float4*)(x + i + 4);
    alignas(16) u16 t[8] = {bfc(a.x), bfc(a.y), bfc(a.z), bfc(a.w),
                            bfc(b.x), bfc(b.y), bfc(b.z), bfc(b.w)};
    *(s8v*)(xb + i) = *(const s8v*)t;
    return;
  }
  const int idx = bid - 4096;  // 0..1023
  const int wz = idx >> 8, wy = (idx >> 4) & 15, wx = idx & 15;
  const float* W;
  u16* O;
  switch (wz) {
    case 0: W = w0; O = o0; break;
    case 1: W = w1; O = o1; break;
    case 2: W = w2; O = o2; break;
    default: W = w3; O = o3; break;
  }
  const int n0 = wx * 64, k0 = wy * 64;
  {
    const int rk = tid >> 2, c0 = (tid & 3) * 16;
#pragma unroll
    for (int u = 0; u < 4; ++u) {
      const float4 v = *(const float4*)&W[(size_t)(k0 + rk) * Cn + n0 + c0 + u * 4];
      Tsh[rk][c0 + u * 4 + 0] = v.x;
      Tsh[rk][c0 + u * 4 + 1] = v.y;
      Tsh[rk][c0 + u * 4 + 2] = v.z;
      Tsh[rk][c0 + u * 4 + 3] = v.w;
    }
  }
  __syncthreads();
  {
    const int rn = tid >> 2, ck0 = (tid & 3) * 16;
    alignas(16) u16 t[16];
#pragma unroll
    for (int u = 0; u < 16; ++u) t[u] = bfc(Tsh[ck0 + u][rn]);
    *(s8v*)&O[(size_t)(n0 + rn) * Cn + k0 + ck0] = *(const s8v*)&t[0];
    *(s8v*)&O[(size_t)(n0 + rn) * Cn + k0 + ck0 + 8] = *(const s8v*)&t[8];
  }
}

// ---------------- GEMM: 256x128, BK=64, 4-phase, 3-deep pipeline ----------
// OUT_MODE 0: bf16  1: V^T head-major pi-permuted  2: fp32  3: bf16 * QSCALE
// LDS per K-tile: A [256][64] (32KB) + B [128][64] (16KB) = 24576 elems.
// 3 tiles = 144KB. Slot (r,c): holds global k-chunk (c ^ (r&7)).
template <int OUT_MODE>
__device__ __forceinline__ void gemm8p(const u16* __restrict__ A,
                                       const u16* __restrict__ Bt,
                                       void* __restrict__ Cout, int bm,
                                       int bn, u16* lds) {
  const int K = Cn;
  const int tid = threadIdx.x;           // 0..511
  const int l = tid & 63, w = tid >> 6;  // 8 waves: 2M x 4N
  const int lr = l & 15, lh = l >> 4;
  const int wm = (w >> 2) * 128, wn = (w & 3) * 32;
  const int sw = lr & 7;
  const u16* Ab = A + (size_t)(bm * 256) * K;
  const u16* Bb = Bt + (size_t)(bn * 128) * K;
  f4v acc[8][2] = {};

  // stage unit u of K-tile kt into buffer buf:
  //   u=0: A rows 0-127, u=1: A rows 128-255, u=2: B rows 0-127
  //   1024 slots, 2 gl_lds16/thread
  auto stage_unit = [&](int buf, int kt, int u) {
    u16* dst = lds + buf * 24576 + (u == 2 ? 16384 : u * 8192);
    const u16* src = (u == 2) ? Bb : (Ab + (size_t)(u * 128) * K);
    {
      const int r = tid >> 3, c = tid & 7;
      gl_lds16(src + (size_t)r * K + kt * 64 + ((c ^ (r & 7)) * 8),
               dst + (size_t)tid * 8);
    }
    {
      const int s = tid + 512;
      const int r = s >> 3, c = s & 7;
      gl_lds16(src + (size_t)r * K + kt * 64 + ((c ^ (r & 7)) * 8),
               dst + (size_t)s * 8);
    }
  };

  // prologue: tiles 0 and 1 (6 loads each); vmcnt(6) -> tile 0 complete
  stage_unit(0, 0, 0);
  stage_unit(0, 0, 1);
  stage_unit(0, 0, 2);
  stage_unit(1, 1, 0);
  stage_unit(1, 1, 1);
  stage_unit(1, 1, 2);
  asm volatile("s_waitcnt vmcnt(6)" ::: "memory");
  __builtin_amdgcn_s_barrier();

  const int NK = K / 64;  // 16
  for (int j = 0; j < NK; ++j) {
    const int cb = j % 3;
    const int nb = (j + 2) % 3;
    const bool more = (j + 2) < NK;
    const u16* Ac = lds + cb * 24576;
    const u16* Bc = Ac + 16384;
#pragma unroll
    for (int p = 0; p < 4; ++p) {
      const int mh = p & 1, kh = p >> 1;
      s8v av[4], bv[2];
#pragma unroll
      for (int i = 0; i < 4; ++i)
        av[i] = *(const s8v*)&Ac[(wm + mh * 64 + i * 16 + lr) * 64 +
                                 (((kh * 4 + lh) ^ sw) * 8)];
#pragma unroll
      for (int jj = 0; jj < 2; ++jj)
        bv[jj] = *(const s8v*)&Bc[(wn + jj * 16 + lr) * 64 +
                                  (((kh * 4 + lh) ^ sw) * 8)];
      if (p < 3) {
        if (more) stage_unit(nb, j + 2, p);
      } else {
        if (more)
          asm volatile("s_waitcnt vmcnt(6)" ::: "memory");
        else
          asm volatile("s_waitcnt vmcnt(0)" ::: "memory");
      }
      __builtin_amdgcn_s_barrier();
      asm volatile("s_waitcnt lgkmcnt(0)" ::: "memory");
      __builtin_amdgcn_sched_barrier(0);
      __builtin_amdgcn_s_setprio(1);
#pragma unroll
      for (int i = 0; i < 4; ++i)
#pragma unroll
        for (int jj = 0; jj < 2; ++jj)
          acc[mh * 4 + i][jj] = mfma16(av[i], bv[jj], acc[mh * 4 + i][jj]);
      __builtin_amdgcn_s_setprio(0);
      __builtin_amdgcn_s_barrier();
    }
  }

  // Epilogue. D layout: col = lane&15, row = (lane>>4)*4 + reg  [m89]
  if (OUT_MODE == 2) {
    float* Cf = (float*)Cout;
#pragma unroll
    for (int i = 0; i < 8; ++i) {
      const int row = bm * 256 + wm + i * 16 + lh * 4;
#pragma unroll
      for (int jj = 0; jj < 2; ++jj) {
        const int col = bn * 128 + wn + jj * 16 + lr;
#pragma unroll
        for (int r = 0; r < 4; ++r)
          Cf[(size_t)(row + r) * Cn + col] = acc[i][jj][r];
      }
    }
  } else if (OUT_MODE == 0 || OUT_MODE == 3) {
    u16* Cb = (u16*)Cout;
    const float sc = (OUT_MODE == 3) ? QSCALE : 1.0f;
#pragma unroll
    for (int i = 0; i < 8; ++i) {
      const int row = bm * 256 + wm + i * 16 + lh * 4;
#pragma unroll
      for (int jj = 0; jj < 2; ++jj) {
        const int col = bn * 128 + wn + jj * 16 + lr;
#pragma unroll
        for (int r = 0; r < 4; ++r)
          Cb[(size_t)(row + r) * Cn + col] = bfc(acc[i][jj][r] * sc);
      }
    }
  } else {
    // V^T head-major pi-permuted: within each 128-t tile, original
    // t = 32p+16s+4lh+j stored at p*32+lh*8+s*4+j (4-groups stay contiguous)
    u16* Vt = (u16*)Cout;
#pragma unroll
    for (int i = 0; i < 8; ++i) {
      const int row0 = bm * 256 + wm + i * 16 + lh * 4;
      const int bq = row0 >> 11;
      const int t0g = row0 & 2047;
      const int tau = t0g & 127;
      const int taup = ((tau >> 5) << 5) | (((tau >> 2) & 3) << 3) |
                       (((tau >> 4) & 1) << 2);
      const int t0p = (t0g & ~127) | taup;
#pragma unroll
      for (int jj = 0; jj < 2; ++jj) {
        const int col = bn * 128 + wn + jj * 16 + lr;
        const int hh = col >> 6, dd = col & 63;
        alignas(8) u16 t4[4];
#pragma unroll
        for (int r = 0; r < 4; ++r) t4[r] = bfc(acc[i][jj][r]);
        *(s4v*)&Vt[((size_t)((bq * 16 + hh) * 64 + dd)) * Tn + t0p] =
            *(const s4v*)t4;
      }
    }
  }
}

// qkv: 768 blocks = 8 XCD x (4 bm-local x 24 (which,bn)); exactly 3 rounds.
__global__ __launch_bounds__(512) void gemm_qkv(
    const u16* __restrict__ A, const u16* __restrict__ btq,
    const u16* __restrict__ btk, const u16* __restrict__ btv,
    u16* __restrict__ qb, u16* __restrict__ kb, u16* __restrict__ vt) {
  __shared__ __align__(16) u16 lds[73728];  // 144 KB
  const int bid = blockIdx.x;               // 0..767
  const int xcd = bid & 7, loc = bid >> 3;  // loc 0..95
  const int bm = xcd * 4 + (loc & 3);       // 0..31 (A-slice 2MB per XCD)
  const int combo = loc >> 2;               // 0..23
  const int which = combo >> 3, bn = combo & 7;
  if (which == 0)
    gemm8p<3>(A, btq, qb, bm, bn, lds);  // Q pre-scaled
  else if (which == 1)
    gemm8p<0>(A, btk, kb, bm, bn, lds);
  else
    gemm8p<1>(A, btv, vt, bm, bn, lds);
}

template <int OUT_MODE>
__global__ __launch_bounds__(512) void gemm_bt(const u16* __restrict__ A,
                                               const u16* __restrict__ Bt,
                                               void* __restrict__ Cout) {
  __shared__ __align__(16) u16 lds[73728];  // 144 KB
  const int bid = blockIdx.x;               // 0..255, exactly 1 round
  const int xcd = bid & 7, loc = bid >> 3;  // loc 0..31
  const int bm = xcd * 4 + (loc & 3);
  const int bn = loc >> 2;  // 0..7
  gemm8p<OUT_MODE>(A, Bt, Cout, bm, bn, lds);
}

// ---------------- Flash attention (round-10 version) ----------------
__device__ __forceinline__ void stage_kv(const u16* __restrict__ kgb,
                                         const u16* __restrict__ vtb,
                                         u16* __restrict__ Kb,
                                         u16* __restrict__ Vb, int k0,
                                         int tid) {
#pragma unroll
  for (int is = 0; is < 2; ++is) {
    const int slot = is * 512 + tid;
    const int row = slot >> 3, ch = slot & 7;
    gl_lds16(kgb + (size_t)(k0 + row) * Cn + ((ch ^ (row & 7)) * 8),
             &Kb[slot * 8]);
  }
#pragma unroll
  for (int is = 0; is < 2; ++is) {
    const int slot = is * 512 + tid;
    const int d = slot >> 4, ch = slot & 15;
    gl_lds16(vtb + (size_t)d * Tn + k0 + ((ch ^ (d & 7)) * 8), &Vb[slot * 8]);
  }
}

__device__ __forceinline__ void attn_step(const s8v (&aq)[2],
                                          const u16* __restrict__ Ks,
                                          const u16* __restrict__ Vs, int kb0,
                                          int kb1, const int (&vch)[4], int ln,
                                          int lh, bool diag, int k0, int qg,
                                          float& m_i, float& l_i, f4v* o) {
  f4v s[8] = {};
  __builtin_amdgcn_s_setprio(1);
#pragma unroll
  for (int n = 0; n < 8; ++n) {
    const s8v bk0 = *(const s8v*)&Ks[kb0 + n * 1024];
    const s8v bk1 = *(const s8v*)&Ks[kb1 + n * 1024];
    s[n] = mfma16(bk0, aq[0], s[n]);  // SWAPPED: S^T[k][q]
    s[n] = mfma16(bk1, aq[1], s[n]);
  }
  __builtin_amdgcn_s_setprio(0);
  float rm = -1e30f;
  if (diag) {
#pragma unroll
    for (int n = 0; n < 8; ++n)
#pragma unroll
      for (int r = 0; r < 4; ++r) {
        float x = s[n][r];
        if (k0 + n * 16 + lh * 4 + r > qg) x = -1e30f;
        s[n][r] = x;
        rm = fmaxf(rm, x);
      }
  } else {
#pragma unroll
    for (int n = 0; n < 8; ++n)
      rm = fmaxf(rm, fmaxf(fmaxf(s[n][0], s[n][1]), fmaxf(s[n][2], s[n][3])));
  }
  if (!__all(rm <= m_i + 11.5f)) {  // T13 defer-max
    float rr = fmaxf(rm, __shfl_xor(rm, 16));
    rr = fmaxf(rr, __shfl_xor(rr, 32));
    const float mnew = fmaxf(m_i, rr);
    const float al = ex2(m_i - mnew);
    m_i = mnew;
    l_i *= al;
#pragma unroll
    for (int r = 0; r < 4; ++r) {
      const float ar = __shfl(al, (ln & 48) | (lh * 4 + r));
#pragma unroll
      for (int n2 = 0; n2 < 4; ++n2) o[n2][r] *= ar;
    }
  }
  s4v pa[8];
  float rs = 0.f;
#pragma unroll
  for (int n = 0; n < 8; ++n) {
    const float p0 = ex2(s[n][0] - m_i);
    const float p1 = ex2(s[n][1] - m_i);
    const float p2 = ex2(s[n][2] - m_i);
    const float p3 = ex2(s[n][3] - m_i);
    rs += (p0 + p1) + (p2 + p3);
    pa[n] = (s4v){(short)bfc(p0), (short)bfc(p1), (short)bfc(p2),
                  (short)bfc(p3)};
  }
  l_i += rs;
  __builtin_amdgcn_s_setprio(1);
#pragma unroll
  for (int n2 = 0; n2 < 4; ++n2) {
#pragma unroll
    for (int p = 0; p < 4; ++p) {
      const s8v vv = *(const s8v*)&Vs[vch[p] + n2 * 2048];
      const s4v lo = {vv[0], vv[1], vv[2], vv[3]};
      const s4v hi = {vv[4], vv[5], vv[6], vv[7]};
      o[n2] = mfma16k16(pa[2 * p], lo, o[n2]);
      o[n2] = mfma16k16(pa[2 * p + 1], hi, o[n2]);
    }
  }
  __builtin_amdgcn_s_setprio(0);
}

__global__ __launch_bounds__(512) void attn_big(const u16* __restrict__ qg,
                                                const u16* __restrict__ kg,
                                                const u16* __restrict__ vtg,
                                                u16* __restrict__ yg) {
  __shared__ __align__(16) u16 Ks0[KVB * 64], Ks1[KVB * 64];  // 16 KB each
  __shared__ __align__(16) u16 Vs0[64 * KVB], Vs1[64 * KVB];  // 16 KB each
  const int tid = threadIdx.x;
  const int ln = tid & 63, w = tid >> 6;  // wave 0..7
  const int lr = ln & 15, lh = ln >> 4;
  const int bid = blockIdx.x;                  // 0..511
  const int wg = (bid & 7) * 64 + (bid >> 3);  // XCD chunking (512 % 8 == 0)
  const int bh = wg >> 3, xp = wg & 7;
  const int b = bh >> 4, h = bh & 15;
  const int tL = xp, tH = NT128 - 1 - xp;
  const int q0L = tL * 128, q0H = tH * 128;
  const u16* kgb = kg + (size_t)(b * Tn) * Cn + h * 64;
  const u16* vtb = vtg + (size_t)(bh * 64) * Tn;
  const int kb0 = lr * 64 + ((lh) ^ (lr & 7)) * 8;
  const int kb1 = lr * 64 + ((4 + lh) ^ (lr & 7)) * 8;
  int vch[4];
#pragma unroll
  for (int p = 0; p < 4; ++p)
    vch[p] = lr * 128 + ((p * 4 + lh) ^ (lr & 7)) * 8;
  s8v aqL[2], aqH[2];
  {
    const int row = w * 16 + lr;
#pragma unroll
    for (int kd = 0; kd < 2; ++kd) {
      aqL[kd] = *(const s8v*)&qg[(size_t)(b * Tn + q0L + row) * Cn + h * 64 +
                                 kd * 32 + lh * 8];
      aqH[kd] = *(const s8v*)&qg[(size_t)(b * Tn + q0H + row) * Cn + h * 64 +
                                 kd * 32 + lh * 8];
    }
  }
  const int qgH = q0H + w * 16 + lr;
  const int qgL = q0L + w * 16 + lr;
  float mL = -1e30f, lL = 0.f, mH = -1e30f, lH = 0.f;
  f4v oL[4] = {}, oH[4] = {};
  stage_kv(kgb, vtb, Ks0, Vs0, 0, tid);
  __syncthreads();  // buf0 ready (barrier drains vmcnt)
  for (int kt = 0; kt <= tH; ++kt) {
    const bool cur = kt & 1;
    const u16* Kb = cur ? Ks1 : Ks0;
    const u16* Vb = cur ? Vs1 : Vs0;
    if (kt < tH)
      stage_kv(kgb, vtb, cur ? Ks0 : Ks1, cur ? Vs0 : Vs1, (kt + 1) * KVB,
               tid);
    attn_step(aqH, Kb, Vb, kb0, kb1, vch, ln, lh, kt == tH, kt * KVB, qgH, mH,
              lH, oH);
    if (kt <= tL)
      attn_step(aqL, Kb, Vb, kb0, kb1, vch, ln, lh, kt == tL, kt * KVB, qgL,
                mL, lL, oL);
    __syncthreads();
  }
  {
    float ls = lH;
    ls += __shfl_xor(ls, 16);
    ls += __shfl_xor(ls, 32);
    const float linv = 1.0f / ls;
#pragma unroll
    for (int r = 0; r < 4; ++r) {
      const float iv = __shfl(linv, (ln & 48) | (lh * 4 + r));
      const int row = q0H + w * 16 + lh * 4 + r;
#pragma unroll
      for (int n2 = 0; n2 < 4; ++n2)
        yg[(size_t)(b * Tn + row) * Cn + h * 64 + n2 * 16 + lr] =
            bfc(oH[n2][r] * iv);
    }
  }
  {
    float ls = lL;
    ls += __shfl_xor(ls, 16);
    ls += __shfl_xor(ls, 32);
    const float linv = 1.0f / ls;
#pragma unroll
    for (int r = 0; r < 4; ++r) {
      const float iv = __shfl(linv, (ln & 48) | (lh * 4 + r));
      const int row = q0L + w * 16 + lh * 4 + r;
#pragma unroll
      for (int n2 = 0; n2 < 4; ++n2)
        yg[(size_t)(b * Tn + row) * Cn + h * 64 + n2 * 16 + lr] =
            bfc(oL[n2][r] * iv);
    }
  }
}

}  // namespace

extern "C" void kernel_launch(void* const* d_in, const int* in_sizes, int n_in,
                              void* d_out, int out_size, void* d_ws,
                              size_t ws_size, hipStream_t stream) {
  (void)in_sizes; (void)n_in; (void)out_size; (void)ws_size;
  const float* x = (const float*)d_in[0];
  const float* Wk = (const float*)d_in[1];
  const float* Wq = (const float*)d_in[2];
  const float* Wv = (const float*)d_in[3];
  const float* Wp = (const float*)d_in[4];
  float* out = (float*)d_out;
  char* ws = (char*)d_ws;

  u16* xb = (u16*)(ws);              // 16.8 MB
  u16* wqt = (u16*)(ws + 16777216);  // 2 MB each
  u16* wkt = (u16*)(ws + 18874368);
  u16* wvt = (u16*)(ws + 20971520);
  u16* wpt = (u16*)(ws + 23068672);
  u16* qb = (u16*)(ws + 25165824);  // 16.8 MB each
  u16* kb = (u16*)(ws + 41943040);
  u16* vt = (u16*)(ws + 58720256);  // head-major V^T [b][h][d][t], pi-permuted
  u16* yb = (u16*)(ws + 75497472);

  prep<<<dim3(5120), dim3(256), 0, stream>>>(x, xb, Wq, Wk, Wv, Wp, wqt, wkt,
                                             wvt, wpt);
  gemm_qkv<<<dim3(768), dim3(512), 0, stream>>>(xb, wqt, wkt, wvt, qb, kb,
                                                vt);
  attn_big<<<dim3(512), dim3(512), 0, stream>>>(qb, kb, vt, yb);
  gemm_bt<2><<<dim3(256), dim3(512), 0, stream>>>(yb, wpt, out);
}